// Round 6
// baseline (215.470 us; speedup 1.0000x reference)
//
#include <hip/hip_runtime.h>
#include <hip/hip_bf16.h>
#include <stdint.h>

// Problem dims (fixed by reference)
#define NB 16384
#define ND 1024
#define NH 2048
#define NE 8
#define NC 3
#define MAXWL 72  // max active (e,mt) 256-row tiles: 16384/256 + 8

typedef __attribute__((ext_vector_type(8))) short short8;
typedef __attribute__((ext_vector_type(4))) short short4v;
typedef __attribute__((ext_vector_type(4))) float f32x4;

// fp32 -> bf16 round-to-nearest-even
__device__ __forceinline__ unsigned short f2bf(float f) {
  union { float f; unsigned int u; } v; v.f = f;
  unsigned int u = v.u;
  return (unsigned short)((u + 0x7fffu + ((u >> 16) & 1u)) >> 16);
}

// async global->LDS, 16B per lane (LDS dest linear in lane order)
__device__ __forceinline__ void glds16(const void* g, void* l) {
  __builtin_amdgcn_global_load_lds(
      (const __attribute__((address_space(1))) void*)g,
      (__attribute__((address_space(3))) void*)l,
      16, 0, 0);
}

// ---------------------------------------------------------------------------
// Kernel 1: router. One wave per row. Fused x->bf16 conversion. fp32 logits
// (argmax must match numpy fp32). Writes topics only — NO atomics.
// ---------------------------------------------------------------------------
__global__ __launch_bounds__(256) void router_kernel(
    const float* __restrict__ x, const float* __restrict__ Wr,
    const float* __restrict__ br, unsigned short* __restrict__ xb,
    int* __restrict__ topics) {
  int w = threadIdx.x >> 6, lane = threadIdx.x & 63;
  int row = blockIdx.x * 4 + w;
  const float* xr = x + (size_t)row * ND;
  unsigned short* xbr = xb + (size_t)row * ND;
  float p[NE] = {0.f, 0.f, 0.f, 0.f, 0.f, 0.f, 0.f, 0.f};
#pragma unroll
  for (int i = 0; i < 4; ++i) {
    int k0 = i * 256 + lane * 4;
    f32x4 xv = *(const f32x4*)(xr + k0);
    short4v s;
#pragma unroll
    for (int j = 0; j < 4; ++j) s[j] = (short)f2bf(xv[j]);
    *(short4v*)(xbr + k0) = s;  // coalesced 8B/lane
#pragma unroll
    for (int j = 0; j < 4; ++j) {
      const f32x4* wp = (const f32x4*)(Wr + (size_t)(k0 + j) * NE);
      f32x4 wa = wp[0], wb = wp[1];  // 32KB Wr lives in cache
      float xj = xv[j];
      p[0] = fmaf(xj, wa[0], p[0]);
      p[1] = fmaf(xj, wa[1], p[1]);
      p[2] = fmaf(xj, wa[2], p[2]);
      p[3] = fmaf(xj, wa[3], p[3]);
      p[4] = fmaf(xj, wb[0], p[4]);
      p[5] = fmaf(xj, wb[1], p[5]);
      p[6] = fmaf(xj, wb[2], p[6]);
      p[7] = fmaf(xj, wb[3], p[7]);
    }
  }
#pragma unroll
  for (int e = 0; e < NE; ++e) {
#pragma unroll
    for (int d = 1; d < 64; d <<= 1) p[e] += __shfl_xor(p[e], d);
  }
  if (lane == 0) {
    float best = -1e30f;
    int bi = 0;
#pragma unroll
    for (int e = 0; e < NE; ++e) {
      float v = p[e] + br[e];
      if (v > best) { best = v; bi = e; }  // strict > : first max (numpy)
    }
    topics[row] = bi;
  }
}

// ---------------------------------------------------------------------------
// Kernel 2: ranker. ONE block, 1024 threads, 16 rows/thread.
// Packed-u16 Hillis-Steele scan of per-thread 8-expert histograms ->
// stable rank -> perm scatter + counts/offsets + worklist (256-row tiles).
// ---------------------------------------------------------------------------
__global__ __launch_bounds__(1024) void ranker_kernel(
    const int* __restrict__ topics, int* __restrict__ perm,
    int* __restrict__ counts, int* __restrict__ offsets,
    int* __restrict__ worklist, int* __restrict__ n_wl) {
  int tid = threadIdx.x;
  __shared__ uint4 sbuf[1024];
  __shared__ int soff[NE];

  int t[16];
  const int4* tp = (const int4*)(topics + tid * 16);
#pragma unroll
  for (int i = 0; i < 4; ++i) {
    int4 v = tp[i];
    t[i * 4 + 0] = v.x; t[i * 4 + 1] = v.y;
    t[i * 4 + 2] = v.z; t[i * 4 + 3] = v.w;
  }
  int h[NE] = {0, 0, 0, 0, 0, 0, 0, 0};
#pragma unroll
  for (int i = 0; i < 16; ++i) {
#pragma unroll
    for (int q = 0; q < NE; ++q) h[q] += (t[i] == q);
  }
  uint4 pk;
  pk.x = (unsigned)h[0] | ((unsigned)h[1] << 16);
  pk.y = (unsigned)h[2] | ((unsigned)h[3] << 16);
  pk.z = (unsigned)h[4] | ((unsigned)h[5] << 16);
  pk.w = (unsigned)h[6] | ((unsigned)h[7] << 16);
  uint4 own = pk;
  sbuf[tid] = pk;
  __syncthreads();
  for (int d = 1; d < 1024; d <<= 1) {
    uint4 v = {0u, 0u, 0u, 0u};
    if (tid >= d) v = sbuf[tid - d];
    __syncthreads();
    pk.x += v.x; pk.y += v.y; pk.z += v.z; pk.w += v.w;
    sbuf[tid] = pk;
    __syncthreads();
  }
  if (tid == 0) {
    uint4 tot = sbuf[1023];
    int c[NE] = {(int)(tot.x & 0xffff), (int)(tot.x >> 16),
                 (int)(tot.y & 0xffff), (int)(tot.y >> 16),
                 (int)(tot.z & 0xffff), (int)(tot.z >> 16),
                 (int)(tot.w & 0xffff), (int)(tot.w >> 16)};
    int s = 0, nw = 0;
    for (int e = 0; e < NE; ++e) {
      counts[e] = c[e];
      offsets[e] = s;
      soff[e] = s;
      s += c[e];
      for (int mt = 0; mt * 256 < c[e]; ++mt) worklist[nw++] = (e << 16) | mt;
    }
    *n_wl = nw;
  }
  __syncthreads();
  uint4 ex;
  ex.x = pk.x - own.x; ex.y = pk.y - own.y;
  ex.z = pk.z - own.z; ex.w = pk.w - own.w;
  int r[NE] = {soff[0] + (int)(ex.x & 0xffff), soff[1] + (int)(ex.x >> 16),
               soff[2] + (int)(ex.y & 0xffff), soff[3] + (int)(ex.y >> 16),
               soff[4] + (int)(ex.z & 0xffff), soff[5] + (int)(ex.z >> 16),
               soff[6] + (int)(ex.w & 0xffff), soff[7] + (int)(ex.w >> 16)};
#pragma unroll
  for (int i = 0; i < 16; ++i) {
    int e = t[i];
    int pos = 0;
#pragma unroll
    for (int q = 0; q < NE; ++q) pos = (e == q) ? r[q] : pos;
    perm[pos] = tid * 16 + i;
#pragma unroll
    for (int q = 0; q < NE; ++q) r[q] += (e == q);
  }
}

// ---------------------------------------------------------------------------
// Kernel 3: W1 [E][D][H] f32 -> W1T [E][H][D] bf16, LDS-tiled, vectorized.
// ---------------------------------------------------------------------------
__global__ __launch_bounds__(256) void w1t_kernel(
    const float* __restrict__ W1, unsigned short* __restrict__ w1t) {
  __shared__ float tile[64][65];
  int bid = blockIdx.x;
  int e = bid >> 9;
  int rem = bid & 511;
  int kb = rem >> 5;
  int hb = rem & 31;
  int t = threadIdx.x;
  const float* src = W1 + ((size_t)e * ND + kb * 64) * NH + hb * 64;
#pragma unroll
  for (int i = 0; i < 4; ++i) {
    int idx = i * 256 + t;
    int kl = idx >> 4;
    int h0 = (idx & 15) * 4;
    f32x4 v = *(const f32x4*)(src + (size_t)kl * NH + h0);
    tile[kl][h0 + 0] = v[0];
    tile[kl][h0 + 1] = v[1];
    tile[kl][h0 + 2] = v[2];
    tile[kl][h0 + 3] = v[3];
  }
  __syncthreads();
  unsigned short* dst = w1t + ((size_t)e * NH + hb * 64) * ND + kb * 64;
#pragma unroll
  for (int i = 0; i < 4; ++i) {
    int idx = i * 256 + t;
    int hl = idx >> 4;
    int kq = (idx & 15) * 4;
    short4v s;
#pragma unroll
    for (int j = 0; j < 4; ++j) s[j] = (short)f2bf(tile[kq + j][hl]);
    *(short4v*)(dst + (size_t)hl * ND + kq) = s;  // 8B/lane coalesced
  }
}

// ---------------------------------------------------------------------------
// Kernel 4: 256x256 8-phase MoE GEMM (T2 swizzle + T3/T4 counted vmcnt + T5).
// 512 thr = 8 waves (2M x 4N), per-wave 128x64 out, BK=64, K=1024 (16 tiles).
// LDS: As/Bs [2 dbuf][2 half][128*64] bf16 = 128KB + ridx.
// Schedule per iteration (2 K-tiles: T0=2i in buf0 @p1-4, T1=2i+1 in buf1
// @p5-8), staging one half-tile per phase into the region freed one barrier
// earlier (B-frags live in regs after each tile's phase 0, freeing B LDS):
//   p1: A(2i+1)h0->buf1   p2: A(2i+1)h1->buf1
//   p3: B(2i+2)h0->buf0   p4: B(2i+2)h1->buf0  + vmcnt(4)
//   p5: A(2i+2)h0->buf0   p6: A(2i+2)h1->buf0
//   p7: B(2i+3)h0->buf1   p8: B(2i+3)h1->buf1  + vmcnt(4)
// vmcnt(4) at p4 retires exactly tile 2i+1; at p8 exactly tile 2i+2.
// Raw s_barrier (NOT __syncthreads: that drains vmcnt(0) and kills the
// pipeline). lgkmcnt(0)+sched_barrier(0) before MFMA (rule #18).
// Last iteration prefetches K-tiles 16/17: reads overshoot into adjacent
// workspace (valid memory) and are never consumed.
// ---------------------------------------------------------------------------
#define MF(a, b, c) __builtin_amdgcn_mfma_f32_16x16x32_bf16((a), (b), (c), 0, 0, 0)
#define RD8(p, off) (*(const short8*)((const char*)(p) + (off)))
#define VW4 asm volatile("s_waitcnt vmcnt(4)" ::: "memory")
#define VWNONE

#define STAGE_A(B, H, KOFF)                                                   \
  do {                                                                        \
    glds16(agp0[H] + (KOFF), (char*)&As[B][H][0] + (size_t)t * 16);           \
    glds16(agp1[H] + (KOFF), (char*)&As[B][H][0] + (size_t)(512 + t) * 16);   \
  } while (0)

#define STAGE_B(B, H, KOFF)                                                   \
  do {                                                                        \
    glds16(bgp0[H] + (KOFF), (char*)&Bs[B][H][0] + (size_t)t * 16);           \
    glds16(bgp1[H] + (KOFF), (char*)&Bs[B][H][0] + (size_t)(512 + t) * 16);   \
  } while (0)

#define PH(B, Q, STAGE_STMT, VW)                                              \
  {                                                                           \
    short8 a00 = RD8(Ah[B], (2 * (Q) + 0) * 2048 + aoff0);                    \
    short8 a01 = RD8(Ah[B], (2 * (Q) + 0) * 2048 + aoff1);                    \
    short8 a10 = RD8(Ah[B], (2 * (Q) + 1) * 2048 + aoff0);                    \
    short8 a11 = RD8(Ah[B], (2 * (Q) + 1) * 2048 + aoff1);                    \
    if ((Q) == 0) {                                                           \
      bf00 = RD8(Bh[B], 0 * 2048 + boff0);                                    \
      bf01 = RD8(Bh[B], 0 * 2048 + boff1);                                    \
      bf10 = RD8(Bh[B], 1 * 2048 + boff0);                                    \
      bf11 = RD8(Bh[B], 1 * 2048 + boff1);                                    \
      bf20 = RD8(Bh[B], 2 * 2048 + boff0);                                    \
      bf21 = RD8(Bh[B], 2 * 2048 + boff1);                                    \
      bf30 = RD8(Bh[B], 3 * 2048 + boff0);                                    \
      bf31 = RD8(Bh[B], 3 * 2048 + boff1);                                    \
    }                                                                         \
    STAGE_STMT;                                                               \
    __builtin_amdgcn_s_barrier();                                             \
    asm volatile("s_waitcnt lgkmcnt(0)" ::: "memory");                        \
    __builtin_amdgcn_sched_barrier(0);                                        \
    __builtin_amdgcn_s_setprio(1);                                            \
    acc[2 * (Q) + 0][0] = MF(a00, bf00, acc[2 * (Q) + 0][0]);                 \
    acc[2 * (Q) + 0][0] = MF(a01, bf01, acc[2 * (Q) + 0][0]);                 \
    acc[2 * (Q) + 0][1] = MF(a00, bf10, acc[2 * (Q) + 0][1]);                 \
    acc[2 * (Q) + 0][1] = MF(a01, bf11, acc[2 * (Q) + 0][1]);                 \
    acc[2 * (Q) + 0][2] = MF(a00, bf20, acc[2 * (Q) + 0][2]);                 \
    acc[2 * (Q) + 0][2] = MF(a01, bf21, acc[2 * (Q) + 0][2]);                 \
    acc[2 * (Q) + 0][3] = MF(a00, bf30, acc[2 * (Q) + 0][3]);                 \
    acc[2 * (Q) + 0][3] = MF(a01, bf31, acc[2 * (Q) + 0][3]);                 \
    acc[2 * (Q) + 1][0] = MF(a10, bf00, acc[2 * (Q) + 1][0]);                 \
    acc[2 * (Q) + 1][0] = MF(a11, bf01, acc[2 * (Q) + 1][0]);                 \
    acc[2 * (Q) + 1][1] = MF(a10, bf10, acc[2 * (Q) + 1][1]);                 \
    acc[2 * (Q) + 1][1] = MF(a11, bf11, acc[2 * (Q) + 1][1]);                 \
    acc[2 * (Q) + 1][2] = MF(a10, bf20, acc[2 * (Q) + 1][2]);                 \
    acc[2 * (Q) + 1][2] = MF(a11, bf21, acc[2 * (Q) + 1][2]);                 \
    acc[2 * (Q) + 1][3] = MF(a10, bf30, acc[2 * (Q) + 1][3]);                 \
    acc[2 * (Q) + 1][3] = MF(a11, bf31, acc[2 * (Q) + 1][3]);                 \
    __builtin_amdgcn_s_setprio(0);                                            \
    VW;                                                                       \
    __builtin_amdgcn_s_barrier();                                             \
  }

__global__ __launch_bounds__(512, 2) void moe_gemm_kernel(
    const unsigned short* __restrict__ xb, const unsigned short* __restrict__ w1t,
    const float* __restrict__ b1, const float* __restrict__ W2,
    const int* __restrict__ perm, const int* __restrict__ counts,
    const int* __restrict__ offsets, const int* __restrict__ worklist,
    const int* __restrict__ n_wl, float* __restrict__ partial) {
  int nt = blockIdx.x & 7;  // B panel; XCD = bid%8 = nt -> B L2-local
  int wi = blockIdx.x >> 3;
  if (wi >= *n_wl) return;
  int item = worklist[wi];
  int e = item >> 16;
  int mt = item & 0xffff;
  int cnt = counts[e];
  int off = offsets[e];
  int t = threadIdx.x;
  int lane = t & 63;
  int wid = t >> 6, wr_ = wid >> 2, wc_ = wid & 3;

  __shared__ __align__(16) unsigned short As[2][2][128 * 64];
  __shared__ __align__(16) unsigned short Bs[2][2][128 * 64];
  __shared__ int ridx[256];

  // hoist epilogue weights: issued BEFORE the __syncthreads below, whose
  // auto vmcnt(0) drain clears them from the vmcnt queue (the K-loop's
  // counted vmcnt(4) must see only glds16 in flight).
  int cg = lane & 15;
  int g = lane >> 4;
  float b1v[4];
  float w2v[4][3];
#pragma unroll
  for (int n = 0; n < 4; ++n) {
    int col = nt * 256 + wc_ * 64 + n * 16 + cg;
    b1v[n] = b1[e * NH + col];
    const float* w2p = W2 + ((size_t)e * NH + col) * NC;
    w2v[n][0] = w2p[0];
    w2v[n][1] = w2p[1];
    w2v[n][2] = w2p[2];
  }

  if (t < 256) {
    int m = mt * 256 + t;
    ridx[t] = perm[off + (m < cnt ? m : cnt - 1)];
  }
  __syncthreads();  // full drain: vmcnt queue empty past this point

  // staging addresses. Thread t stages, per matrix per half, rows
  // r(j)=j*64+(t>>3), 16B chunk c=t&7, source chunk swizzled cs=c^(r&7)
  // ((j*64+r0)&7==r0&7, so cs is j-independent). LDS dest linear.
  int r0 = t >> 3;
  int cs0 = (t & 7) ^ (r0 & 7);
  const unsigned short* agp0[2];
  const unsigned short* agp1[2];
  const unsigned short* bgp0[2];
  const unsigned short* bgp1[2];
#pragma unroll
  for (int h = 0; h < 2; ++h) {
    agp0[h] = xb + (size_t)ridx[h * 128 + r0] * ND + cs0 * 8;
    agp1[h] = xb + (size_t)ridx[h * 128 + 64 + r0] * ND + cs0 * 8;
    bgp0[h] = w1t + ((size_t)(e * NH + nt * 256 + h * 128 + r0)) * ND + cs0 * 8;
    bgp1[h] = w1t + ((size_t)(e * NH + nt * 256 + h * 128 + 64 + r0)) * ND + cs0 * 8;
  }

  // ds_read bases: wave wr_ reads A-half wr_; wave wc_ reads B-half wc_>>1.
  const char* Ah[2] = {(const char*)&As[0][wr_][0], (const char*)&As[1][wr_][0]};
  const char* Bh[2] = {(const char*)&Bs[0][wc_ >> 1][0],
                       (const char*)&Bs[1][wc_ >> 1][0]};
  int lane4 = lane & 15, lanehi = lane >> 4;
  int aoff0 = lane4 * 128 + (((0 * 4 + lanehi) ^ (lane4 & 7)) * 16);
  int aoff1 = lane4 * 128 + (((1 * 4 + lanehi) ^ (lane4 & 7)) * 16);
  int boff0 = ((wc_ & 1) * 64 + lane4) * 128 + (((0 * 4 + lanehi) ^ (lane4 & 7)) * 16);
  int boff1 = ((wc_ & 1) * 64 + lane4) * 128 + (((1 * 4 + lanehi) ^ (lane4 & 7)) * 16);

  f32x4 acc[8][4];
#pragma unroll
  for (int m = 0; m < 8; ++m)
#pragma unroll
    for (int n = 0; n < 4; ++n) acc[m][n] = (f32x4){0.f, 0.f, 0.f, 0.f};
  short8 bf00, bf01, bf10, bf11, bf20, bf21, bf30, bf31;

  // prologue: tile0 (A+B) + B1; vmcnt(4) retires exactly tile 0.
  STAGE_A(0, 0, 0);
  STAGE_A(0, 1, 0);
  STAGE_B(0, 0, 0);
  STAGE_B(0, 1, 0);
  STAGE_B(1, 0, 64);
  STAGE_B(1, 1, 64);
  asm volatile("s_waitcnt vmcnt(4)" ::: "memory");
  __builtin_amdgcn_s_barrier();

#pragma unroll 1
  for (int it = 0; it < 8; ++it) {
    int k1 = (2 * it + 1) * 64;
    int k2 = k1 + 64;
    int k3 = k1 + 128;
    PH(0, 0, STAGE_A(1, 0, k1), VWNONE);
    PH(0, 1, STAGE_A(1, 1, k1), VWNONE);
    PH(0, 2, STAGE_B(0, 0, k2), VWNONE);
    PH(0, 3, STAGE_B(0, 1, k2), VW4);
    PH(1, 0, STAGE_A(0, 0, k2), VWNONE);
    PH(1, 1, STAGE_A(0, 1, k2), VWNONE);
    PH(1, 2, STAGE_B(1, 0, k3), VWNONE);
    PH(1, 3, STAGE_B(1, 1, k3), VW4);
  }
  // drain the final (unconsumed) prefetches before LDS dealloc at endpgm
  asm volatile("s_waitcnt vmcnt(0)" ::: "memory");

  // Epilogue: h = relu(acc + b1); partial[wi][nt][wc_][row][c] = this wave's
  // 64-h-col contribution.  C/D frag: col=lane&15, row=(lane>>4)*4+i [m89].
  float* pbase = partial + (((size_t)(wi * 8 + nt)) * 4 + wc_) * 256 * NC;
#pragma unroll
  for (int m = 0; m < 8; ++m) {
#pragma unroll
    for (int i = 0; i < 4; ++i) {
      float s0 = 0.f, s1 = 0.f, s2 = 0.f;
#pragma unroll
      for (int n = 0; n < 4; ++n) {
        float h = acc[m][n][i] + b1v[n];
        h = h > 0.f ? h : 0.f;
        s0 = fmaf(h, w2v[n][0], s0);
        s1 = fmaf(h, w2v[n][1], s1);
        s2 = fmaf(h, w2v[n][2], s2);
      }
#pragma unroll
      for (int d = 1; d < 16; d <<= 1) {
        s0 += __shfl_xor(s0, d);
        s1 += __shfl_xor(s1, d);
        s2 += __shfl_xor(s2, d);
      }
      if (cg == 0) {
        int rloc = wr_ * 128 + m * 16 + g * 4 + i;
        float* pp = pbase + rloc * NC;
        pp[0] = s0;
        pp[1] = s1;
        pp[2] = s2;
      }
    }
  }
}

// ---------------------------------------------------------------------------
// Kernel 5: reduce partials over (nt x wc) = 32 slots; out = b2[e] + sum.
// One block per worklist tile; 768 threads = (row,c); stride-768 coalesced.
// ---------------------------------------------------------------------------
__global__ __launch_bounds__(768) void reduce_kernel(
    const float* __restrict__ partial, const float* __restrict__ b2,
    const int* __restrict__ perm, const int* __restrict__ counts,
    const int* __restrict__ offsets, const int* __restrict__ worklist,
    const int* __restrict__ n_wl, float* __restrict__ out) {
  int wi = blockIdx.x;
  if (wi >= *n_wl) return;
  int item = worklist[wi];
  int e = item >> 16;
  int mt = item & 0xffff;
  int cnt = counts[e];
  int off = offsets[e];
  int j = threadIdx.x;  // row*3 + c
  int r = j / 3, c = j - r * 3;
  int m = mt * 256 + r;
  if (m >= cnt) return;
  const float* p = partial + (size_t)wi * 32 * 768 + j;
  float s = 0.f;
#pragma unroll
  for (int q = 0; q < 32; ++q) s += p[q * 768];
  int tok = perm[off + m];
  out[tok * NC + c] = b2[e * NC + c] + s;
}

// ---------------------------------------------------------------------------
// Workspace layout (~74.3 MB):
//   [0,   32MiB)       xb  bf16 [16384][1024]
//   [32,  64MiB)       W1T bf16 [8][2048][1024]
//   [64MiB, +132KB)    topics[16384], perm[16384], counts[8], offsets[8],
//                      worklist[256], n_wl
//   [64MiB+132KB, ...) partial f32 [72*8][4][256][3]  (7.08 MB)
// (gemm tail-K prefetch overshoots <=2.3KB into adjacent workspace regions —
//  valid memory, never consumed; duplicate tail rows guarded in reduce.)
// ---------------------------------------------------------------------------
extern "C" void kernel_launch(void* const* d_in, const int* in_sizes, int n_in,
                              void* d_out, int out_size, void* d_ws,
                              size_t ws_size, hipStream_t stream) {
  const float* x = (const float*)d_in[0];
  const float* Wr = (const float*)d_in[1];
  const float* br = (const float*)d_in[2];
  const float* W1 = (const float*)d_in[3];
  const float* b1 = (const float*)d_in[4];
  const float* W2 = (const float*)d_in[5];
  const float* b2 = (const float*)d_in[6];
  float* out = (float*)d_out;

  char* ws = (char*)d_ws;
  unsigned short* xb = (unsigned short*)ws;
  unsigned short* w1t = (unsigned short*)(ws + (size_t)33554432);
  int* topics = (int*)(ws + (size_t)67108864);
  int* perm = topics + NB;
  int* counts = perm + NB;
  int* offsets = counts + NE;
  int* worklist = offsets + NE;
  int* n_wl = worklist + 256;
  float* partial = (float*)(ws + (size_t)67108864 + 135168);

  router_kernel<<<NB / 4, 256, 0, stream>>>(x, Wr, br, xb, topics);
  ranker_kernel<<<1, 1024, 0, stream>>>(topics, perm, counts, offsets,
                                        worklist, n_wl);
  w1t_kernel<<<NE * 16 * 32, 256, 0, stream>>>(W1, w1t);
  moe_gemm_kernel<<<MAXWL * 8, 512, 0, stream>>>(xb, w1t, b1, W2, perm,
                                                 counts, offsets, worklist,
                                                 n_wl, partial);
  reduce_kernel<<<MAXWL, 768, 0, stream>>>(partial, b2, perm, counts, offsets,
                                           worklist, n_wl, out);
}

// Round 7
// 208.612 us; speedup vs baseline: 1.0329x; 1.0329x over previous
//
#include <hip/hip_runtime.h>
#include <hip/hip_bf16.h>
#include <stdint.h>

// Problem dims (fixed by reference)
#define NB 16384
#define ND 1024
#define NH 2048
#define NE 8
#define NC 3
#define MAXWL 136  // max active (e,mt) 128-row tiles: 16384/128 + 8

typedef __attribute__((ext_vector_type(8))) short short8;
typedef __attribute__((ext_vector_type(4))) short short4v;
typedef __attribute__((ext_vector_type(4))) float f32x4;

// fp32 -> bf16 round-to-nearest-even
__device__ __forceinline__ unsigned short f2bf(float f) {
  union { float f; unsigned int u; } v; v.f = f;
  unsigned int u = v.u;
  return (unsigned short)((u + 0x7fffu + ((u >> 16) & 1u)) >> 16);
}

// async global->LDS, 16B per lane (LDS dest linear in lane order)
__device__ __forceinline__ void glds16(const void* g, void* l) {
  __builtin_amdgcn_global_load_lds(
      (const __attribute__((address_space(1))) void*)g,
      (__attribute__((address_space(3))) void*)l,
      16, 0, 0);
}

// ---------------------------------------------------------------------------
// Kernel 1: router. One wave per row. Fused x->bf16 conversion. fp32 logits
// (argmax must match numpy fp32). Writes topics only — NO atomics.
// ---------------------------------------------------------------------------
__global__ __launch_bounds__(256) void router_kernel(
    const float* __restrict__ x, const float* __restrict__ Wr,
    const float* __restrict__ br, unsigned short* __restrict__ xb,
    int* __restrict__ topics) {
  int w = threadIdx.x >> 6, lane = threadIdx.x & 63;
  int row = blockIdx.x * 4 + w;
  const float* xr = x + (size_t)row * ND;
  unsigned short* xbr = xb + (size_t)row * ND;
  float p[NE] = {0.f, 0.f, 0.f, 0.f, 0.f, 0.f, 0.f, 0.f};
#pragma unroll
  for (int i = 0; i < 4; ++i) {
    int k0 = i * 256 + lane * 4;
    f32x4 xv = *(const f32x4*)(xr + k0);
    short4v s;
#pragma unroll
    for (int j = 0; j < 4; ++j) s[j] = (short)f2bf(xv[j]);
    *(short4v*)(xbr + k0) = s;  // coalesced 8B/lane
#pragma unroll
    for (int j = 0; j < 4; ++j) {
      const f32x4* wp = (const f32x4*)(Wr + (size_t)(k0 + j) * NE);
      f32x4 wa = wp[0], wb = wp[1];  // 32KB Wr lives in cache
      float xj = xv[j];
      p[0] = fmaf(xj, wa[0], p[0]);
      p[1] = fmaf(xj, wa[1], p[1]);
      p[2] = fmaf(xj, wa[2], p[2]);
      p[3] = fmaf(xj, wa[3], p[3]);
      p[4] = fmaf(xj, wb[0], p[4]);
      p[5] = fmaf(xj, wb[1], p[5]);
      p[6] = fmaf(xj, wb[2], p[6]);
      p[7] = fmaf(xj, wb[3], p[7]);
    }
  }
#pragma unroll
  for (int e = 0; e < NE; ++e) {
#pragma unroll
    for (int d = 1; d < 64; d <<= 1) p[e] += __shfl_xor(p[e], d);
  }
  if (lane == 0) {
    float best = -1e30f;
    int bi = 0;
#pragma unroll
    for (int e = 0; e < NE; ++e) {
      float v = p[e] + br[e];
      if (v > best) { best = v; bi = e; }  // strict > : first max (numpy)
    }
    topics[row] = bi;
  }
}

// ---------------------------------------------------------------------------
// Kernel 2: FUSED ranker + W1 transpose (round-6 lesson: 5 serial launches +
// a 1-CU ranker cost ~90us of "rest"; the ranker has no dependency on w1t,
// so run it as one extra block of the transpose launch — it hides under the
// 96MB transpose stream and saves a launch boundary).
//   blocks 0..4095  : W1 [E][D][H] f32 -> W1T [E][H][D] bf16 (one 64x64 tile
//                     per block, 1024 thr, f32x4 reads / short4 writes)
//   block  4096     : ranker — packed-u16 Hillis-Steele scan of per-thread
//                     8-expert histograms -> stable rank -> perm scatter +
//                     counts/offsets + worklist (128-row tiles).
// ---------------------------------------------------------------------------
__global__ __launch_bounds__(1024) void ranker_w1t_kernel(
    const int* __restrict__ topics, const float* __restrict__ W1,
    unsigned short* __restrict__ w1t, int* __restrict__ perm,
    int* __restrict__ counts, int* __restrict__ offsets,
    int* __restrict__ worklist, int* __restrict__ n_wl) {
  __shared__ float tile[64][65];
  __shared__ uint4 sbuf[1024];
  __shared__ int soff[NE];
  int tid = threadIdx.x;

  if (blockIdx.x < 4096) {
    // ---- W1 transpose+convert: one 64x64 tile ----
    int wid = blockIdx.x;
    int e = wid >> 9;
    int rem = wid & 511;
    int kb = rem >> 5;
    int hb = rem & 31;
    const float* src = W1 + ((size_t)e * ND + kb * 64) * NH + hb * 64;
    int kl = tid >> 4;
    int h0 = (tid & 15) * 4;
    f32x4 v = *(const f32x4*)(src + (size_t)kl * NH + h0);
    tile[kl][h0 + 0] = v[0];
    tile[kl][h0 + 1] = v[1];
    tile[kl][h0 + 2] = v[2];
    tile[kl][h0 + 3] = v[3];
    __syncthreads();
    unsigned short* dst = w1t + ((size_t)e * NH + hb * 64) * ND + kb * 64;
    int hl = tid >> 4;
    int kq = (tid & 15) * 4;
    short4v s;
#pragma unroll
    for (int j = 0; j < 4; ++j) s[j] = (short)f2bf(tile[kq + j][hl]);
    *(short4v*)(dst + (size_t)hl * ND + kq) = s;  // 8B/lane coalesced
    return;
  }

  // ---- ranker ----
  int t[16];
  const int4* tp = (const int4*)(topics + tid * 16);
#pragma unroll
  for (int i = 0; i < 4; ++i) {
    int4 v = tp[i];
    t[i * 4 + 0] = v.x; t[i * 4 + 1] = v.y;
    t[i * 4 + 2] = v.z; t[i * 4 + 3] = v.w;
  }
  int h[NE] = {0, 0, 0, 0, 0, 0, 0, 0};
#pragma unroll
  for (int i = 0; i < 16; ++i) {
#pragma unroll
    for (int q = 0; q < NE; ++q) h[q] += (t[i] == q);
  }
  uint4 pk;
  pk.x = (unsigned)h[0] | ((unsigned)h[1] << 16);
  pk.y = (unsigned)h[2] | ((unsigned)h[3] << 16);
  pk.z = (unsigned)h[4] | ((unsigned)h[5] << 16);
  pk.w = (unsigned)h[6] | ((unsigned)h[7] << 16);
  uint4 own = pk;
  sbuf[tid] = pk;
  __syncthreads();
  for (int d = 1; d < 1024; d <<= 1) {
    uint4 v = {0u, 0u, 0u, 0u};
    if (tid >= d) v = sbuf[tid - d];
    __syncthreads();
    pk.x += v.x; pk.y += v.y; pk.z += v.z; pk.w += v.w;
    sbuf[tid] = pk;
    __syncthreads();
  }
  if (tid == 0) {
    uint4 tot = sbuf[1023];
    int c[NE] = {(int)(tot.x & 0xffff), (int)(tot.x >> 16),
                 (int)(tot.y & 0xffff), (int)(tot.y >> 16),
                 (int)(tot.z & 0xffff), (int)(tot.z >> 16),
                 (int)(tot.w & 0xffff), (int)(tot.w >> 16)};
    int s = 0, nw = 0;
    for (int e = 0; e < NE; ++e) {
      counts[e] = c[e];
      offsets[e] = s;
      soff[e] = s;
      s += c[e];
      for (int mt = 0; mt * 128 < c[e]; ++mt) worklist[nw++] = (e << 16) | mt;
    }
    *n_wl = nw;
  }
  __syncthreads();
  uint4 ex;
  ex.x = pk.x - own.x; ex.y = pk.y - own.y;
  ex.z = pk.z - own.z; ex.w = pk.w - own.w;
  int r[NE] = {soff[0] + (int)(ex.x & 0xffff), soff[1] + (int)(ex.x >> 16),
               soff[2] + (int)(ex.y & 0xffff), soff[3] + (int)(ex.y >> 16),
               soff[4] + (int)(ex.z & 0xffff), soff[5] + (int)(ex.z >> 16),
               soff[6] + (int)(ex.w & 0xffff), soff[7] + (int)(ex.w >> 16)};
#pragma unroll
  for (int i = 0; i < 16; ++i) {
    int e = t[i];
    int pos = 0;
#pragma unroll
    for (int q = 0; q < NE; ++q) pos = (e == q) ? r[q] : pos;
    perm[pos] = tid * 16 + i;
#pragma unroll
    for (int q = 0; q < NE; ++q) r[q] += (e == q);
  }
}

// ---------------------------------------------------------------------------
// Kernel 3: fused gathered GEMM + bias/relu + W2 reduce -> PARTIALS.
// Round-7 change vs round 5: BK 64 -> 32. LDS 64.5KB -> 33KB => 4 blocks/CU
// (16 waves/CU). Round-6 lesson: residency/overlap beats phase-schedule
// depth at this grid size — the 2-phase stall (stage+drain+barrier) is
// hidden by 4-deep block co-residency instead of intra-block pipelining.
// 128x128 tile, 4 waves x (4x4) 16x16x32 bf16 MFMA frags, 32 K-tiles.
// LDS chunk XOR-swizzle is the BK-scaled analog of the proven round-5 one
// (slot(r,c) holds global chunk c^(r&3); read ch = g^(lane4&3)).
// Epilogue: per-wave partial[wi][nt][wc][128][3]; reduce sums 32 slots.
// ---------------------------------------------------------------------------
#define MF(a, b, c) __builtin_amdgcn_mfma_f32_16x16x32_bf16((a), (b), (c), 0, 0, 0)

#define STAGE(AS, BS, kt)                                       \
  do {                                                          \
    glds16(aptr0 + (kt), (char*)(AS) + (size_t)t * 16);         \
    glds16(aptr1 + (kt), (char*)(AS) + (size_t)(256 + t) * 16); \
    glds16(bptr0 + (kt), (char*)(BS) + (size_t)t * 16);         \
    glds16(bptr1 + (kt), (char*)(BS) + (size_t)(256 + t) * 16); \
  } while (0)

#define COMPUTE(AS, BS)                                               \
  do {                                                                \
    short8 af_[4], bf_[4];                                            \
    _Pragma("unroll") for (int m_ = 0; m_ < 4; ++m_)                  \
        af_[m_] = *(const short8*)&(AS)[arow_e + m_ * 512 + ch8];     \
    _Pragma("unroll") for (int n_ = 0; n_ < 4; ++n_)                  \
        bf_[n_] = *(const short8*)&(BS)[brow_e + n_ * 512 + ch8];     \
    _Pragma("unroll") for (int m_ = 0; m_ < 4; ++m_)                  \
        _Pragma("unroll") for (int n_ = 0; n_ < 4; ++n_)              \
            acc[m_][n_] = MF(af_[m_], bf_[n_], acc[m_][n_]);          \
  } while (0)

__global__ __launch_bounds__(256, 4) void moe_gemm_kernel(
    const unsigned short* __restrict__ xb, const unsigned short* __restrict__ w1t,
    const float* __restrict__ b1, const float* __restrict__ W2,
    const int* __restrict__ perm, const int* __restrict__ counts,
    const int* __restrict__ offsets, const int* __restrict__ worklist,
    const int* __restrict__ n_wl, float* __restrict__ partial) {
  int nt = blockIdx.x & 15;  // B panel; XCD = bid%8 -> B L2-local
  int wi = blockIdx.x >> 4;
  if (wi >= *n_wl) return;
  int item = worklist[wi];
  int e = item >> 16;
  int mt = item & 0xffff;
  int cnt = counts[e];
  int off = offsets[e];
  int t = threadIdx.x;
  int lane = t & 63;
  int w = t >> 6, wr = w >> 1, wc = w & 1;

  __shared__ int ridx[128];
  __shared__ unsigned short As0[128 * 32];  // slot(r,c) holds chunk c^(r&3)
  __shared__ unsigned short Bs0[128 * 32];
  __shared__ unsigned short As1[128 * 32];
  __shared__ unsigned short Bs1[128 * 32];

  if (t < 128) {
    int m = mt * 128 + t;
    ridx[t] = perm[off + (m < cnt ? m : cnt - 1)];
  }
  __syncthreads();

  // staging: thread t covers 16B chunks idx=t and idx=256+t of each tile.
  // idx -> row r=idx>>2, chunk c=idx&3; source chunk swizzled cs=c^(r&3).
  // (r for idx=256+t is 64+(t>>2): (64+r0)&3 == r0&3, so cs is shared.)
  int r0 = t >> 2;
  int cs0 = (t & 3) ^ (r0 & 3);
  const unsigned short* aptr0 = xb + (size_t)ridx[r0] * ND + cs0 * 8;
  const unsigned short* aptr1 = xb + (size_t)ridx[64 + r0] * ND + cs0 * 8;
  const unsigned short* bptr0 =
      w1t + ((size_t)(e * NH + nt * 128 + r0)) * ND + cs0 * 8;
  const unsigned short* bptr1 =
      w1t + ((size_t)(e * NH + nt * 128 + 64 + r0)) * ND + cs0 * 8;

  // hoist epilogue weights above K-loop
  int cg = lane & 15;
  int g = lane >> 4;
  float b1v[4];
  float w2v[4][3];
#pragma unroll
  for (int n = 0; n < 4; ++n) {
    int col = nt * 128 + wc * 64 + n * 16 + cg;
    b1v[n] = b1[e * NH + col];
    const float* w2p = W2 + ((size_t)e * NH + col) * NC;
    w2v[n][0] = w2p[0];
    w2v[n][1] = w2p[1];
    w2v[n][2] = w2p[2];
  }

  f32x4 acc[4][4];
#pragma unroll
  for (int m = 0; m < 4; ++m)
#pragma unroll
    for (int n = 0; n < 4; ++n) acc[m][n] = (f32x4){0.f, 0.f, 0.f, 0.f};

  int arow_e = (wr * 64 + cg) * 32;
  int brow_e = (wc * 64 + cg) * 32;
  int ch8 = (g ^ (cg & 3)) * 8;  // swizzled chunk for this lane's k-slice

  // double-buffered K-loop: 32 tiles of BK=32
  STAGE(As0, Bs0, 0);
  __syncthreads();
#pragma unroll 1
  for (int it = 0; it < 15; ++it) {
    int kb = it * 64;
    STAGE(As1, Bs1, kb + 32);
    COMPUTE(As0, Bs0);
    __syncthreads();
    STAGE(As0, Bs0, kb + 64);
    COMPUTE(As1, Bs1);
    __syncthreads();
  }
  STAGE(As1, Bs1, 992);
  COMPUTE(As0, Bs0);  // tile kt=960
  __syncthreads();
  COMPUTE(As1, Bs1);  // tile kt=992

  // Epilogue: h = relu(acc + b1); partial[wi][nt][wc][row][c] = this wave's
  // 64-h-col contribution.  C/D frag: col=lane&15, row=(lane>>4)*4+i [m89].
  float* pbase = partial + (((size_t)(wi * 16 + nt)) * 2 + wc) * 128 * NC;
#pragma unroll
  for (int m = 0; m < 4; ++m) {
#pragma unroll
    for (int i = 0; i < 4; ++i) {
      float s0 = 0.f, s1 = 0.f, s2 = 0.f;
#pragma unroll
      for (int n = 0; n < 4; ++n) {
        float h = acc[m][n][i] + b1v[n];
        h = h > 0.f ? h : 0.f;
        s0 = fmaf(h, w2v[n][0], s0);
        s1 = fmaf(h, w2v[n][1], s1);
        s2 = fmaf(h, w2v[n][2], s2);
      }
#pragma unroll
      for (int d = 1; d < 16; d <<= 1) {
        s0 += __shfl_xor(s0, d);
        s1 += __shfl_xor(s1, d);
        s2 += __shfl_xor(s2, d);
      }
      if (cg == 0) {
        int rloc = wr * 64 + m * 16 + g * 4 + i;
        float* pp = pbase + rloc * NC;
        pp[0] = s0;
        pp[1] = s1;
        pp[2] = s2;
      }
    }
  }
}

// ---------------------------------------------------------------------------
// Kernel 4: reduce partials over (nt, wc) and write out = b2[e] + sum.
// One block per worklist tile; 384 threads = (row,c) pairs; sum 32 slots.
// ---------------------------------------------------------------------------
__global__ __launch_bounds__(384) void reduce_kernel(
    const float* __restrict__ partial, const float* __restrict__ b2,
    const int* __restrict__ perm, const int* __restrict__ counts,
    const int* __restrict__ offsets, const int* __restrict__ worklist,
    const int* __restrict__ n_wl, float* __restrict__ out) {
  int wi = blockIdx.x;
  if (wi >= *n_wl) return;
  int item = worklist[wi];
  int e = item >> 16;
  int mt = item & 0xffff;
  int cnt = counts[e];
  int off = offsets[e];
  int j = threadIdx.x;  // row*3 + c
  int r = j / 3, c = j - r * 3;
  int m = mt * 128 + r;
  if (m >= cnt) return;
  const float* p = partial + (size_t)wi * 32 * 384 + j;
  float s = 0.f;
#pragma unroll
  for (int q = 0; q < 32; ++q) s += p[q * 384];
  int tok = perm[off + m];
  out[tok * NC + c] = b2[e * NC + c] + s;
}

// ---------------------------------------------------------------------------
// Workspace layout (~74 MB):
//   [0,   32MiB)       xb  bf16 [16384][1024]
//   [32,  64MiB)       W1T bf16 [8][2048][1024]
//   [64MiB, +132KB)    topics[16384], perm[16384], counts[8], offsets[8],
//                      worklist[256], n_wl
//   [64MiB+132KB, ...) partial f32 [136*16][2][128][3]  (6.68 MB)
// (gemm A-tail duplicate rows produce partials for rloc>=cnt; reduce guards.)
// ---------------------------------------------------------------------------
extern "C" void kernel_launch(void* const* d_in, const int* in_sizes, int n_in,
                              void* d_out, int out_size, void* d_ws,
                              size_t ws_size, hipStream_t stream) {
  const float* x = (const float*)d_in[0];
  const float* Wr = (const float*)d_in[1];
  const float* br = (const float*)d_in[2];
  const float* W1 = (const float*)d_in[3];
  const float* b1 = (const float*)d_in[4];
  const float* W2 = (const float*)d_in[5];
  const float* b2 = (const float*)d_in[6];
  float* out = (float*)d_out;

  char* ws = (char*)d_ws;
  unsigned short* xb = (unsigned short*)ws;
  unsigned short* w1t = (unsigned short*)(ws + (size_t)33554432);
  int* topics = (int*)(ws + (size_t)67108864);
  int* perm = topics + NB;
  int* counts = perm + NB;
  int* offsets = counts + NE;
  int* worklist = offsets + NE;
  int* n_wl = worklist + 256;
  float* partial = (float*)(ws + (size_t)67108864 + 135168);

  router_kernel<<<NB / 4, 256, 0, stream>>>(x, Wr, br, xb, topics);
  ranker_w1t_kernel<<<4097, 1024, 0, stream>>>(topics, W1, w1t, perm, counts,
                                               offsets, worklist, n_wl);
  moe_gemm_kernel<<<MAXWL * 16, 256, 0, stream>>>(xb, w1t, b1, W2, perm,
                                                  counts, offsets, worklist,
                                                  n_wl, partial);
  reduce_kernel<<<MAXWL, 384, 0, stream>>>(partial, b2, perm, counts, offsets,
                                           worklist, n_wl, out);
}

// Round 8
// 200.113 us; speedup vs baseline: 1.0767x; 1.0425x over previous
//
#include <hip/hip_runtime.h>
#include <hip/hip_bf16.h>
#include <stdint.h>

// Problem dims (fixed by reference)
#define NB 16384
#define ND 1024
#define NH 2048
#define NE 8
#define NC 3
#define MAXWL 136  // max active (e,mt) 128-row tiles: 16384/128 + 8

typedef __attribute__((ext_vector_type(8))) short short8;
typedef __attribute__((ext_vector_type(4))) short short4v;
typedef __attribute__((ext_vector_type(4))) float f32x4;

// fp32 -> bf16 round-to-nearest-even
__device__ __forceinline__ unsigned short f2bf(float f) {
  union { float f; unsigned int u; } v; v.f = f;
  unsigned int u = v.u;
  return (unsigned short)((u + 0x7fffu + ((u >> 16) & 1u)) >> 16);
}

// async global->LDS, 16B per lane (LDS dest linear in lane order)
__device__ __forceinline__ void glds16(const void* g, void* l) {
  __builtin_amdgcn_global_load_lds(
      (const __attribute__((address_space(1))) void*)g,
      (__attribute__((address_space(3))) void*)l,
      16, 0, 0);
}

// ---------------------------------------------------------------------------
// Kernel 1: router. One wave per row. Fused x->bf16 conversion. fp32 logits
// (argmax must match numpy fp32). Writes topics only — NO atomics.
// ---------------------------------------------------------------------------
__global__ __launch_bounds__(256) void router_kernel(
    const float* __restrict__ x, const float* __restrict__ Wr,
    const float* __restrict__ br, unsigned short* __restrict__ xb,
    int* __restrict__ topics) {
  int w = threadIdx.x >> 6, lane = threadIdx.x & 63;
  int row = blockIdx.x * 4 + w;
  const float* xr = x + (size_t)row * ND;
  unsigned short* xbr = xb + (size_t)row * ND;
  float p[NE] = {0.f, 0.f, 0.f, 0.f, 0.f, 0.f, 0.f, 0.f};
#pragma unroll
  for (int i = 0; i < 4; ++i) {
    int k0 = i * 256 + lane * 4;
    f32x4 xv = *(const f32x4*)(xr + k0);
    short4v s;
#pragma unroll
    for (int j = 0; j < 4; ++j) s[j] = (short)f2bf(xv[j]);
    *(short4v*)(xbr + k0) = s;  // coalesced 8B/lane
#pragma unroll
    for (int j = 0; j < 4; ++j) {
      const f32x4* wp = (const f32x4*)(Wr + (size_t)(k0 + j) * NE);
      f32x4 wa = wp[0], wb = wp[1];  // 32KB Wr lives in cache
      float xj = xv[j];
      p[0] = fmaf(xj, wa[0], p[0]);
      p[1] = fmaf(xj, wa[1], p[1]);
      p[2] = fmaf(xj, wa[2], p[2]);
      p[3] = fmaf(xj, wa[3], p[3]);
      p[4] = fmaf(xj, wb[0], p[4]);
      p[5] = fmaf(xj, wb[1], p[5]);
      p[6] = fmaf(xj, wb[2], p[6]);
      p[7] = fmaf(xj, wb[3], p[7]);
    }
  }
#pragma unroll
  for (int e = 0; e < NE; ++e) {
#pragma unroll
    for (int d = 1; d < 64; d <<= 1) p[e] += __shfl_xor(p[e], d);
  }
  if (lane == 0) {
    float best = -1e30f;
    int bi = 0;
#pragma unroll
    for (int e = 0; e < NE; ++e) {
      float v = p[e] + br[e];
      if (v > best) { best = v; bi = e; }  // strict > : first max (numpy)
    }
    topics[row] = bi;
  }
}

// ---------------------------------------------------------------------------
// Kernel 2: FUSED ranker + W1 transpose.
//   blocks 0..4095  : W1 [E][D][H] f32 -> W1T [E][H][D] bf16 (one 64x64 tile
//                     per block, 1024 thr, f32x4 reads / short4 writes)
//   block  4096     : ranker — packed-u16 Hillis-Steele scan of per-thread
//                     8-expert histograms -> stable rank -> perm scatter +
//                     counts/offsets + worklist (128-row tiles).
// ---------------------------------------------------------------------------
__global__ __launch_bounds__(1024) void ranker_w1t_kernel(
    const int* __restrict__ topics, const float* __restrict__ W1,
    unsigned short* __restrict__ w1t, int* __restrict__ perm,
    int* __restrict__ counts, int* __restrict__ offsets,
    int* __restrict__ worklist, int* __restrict__ n_wl) {
  __shared__ float tile[64][65];
  __shared__ uint4 sbuf[1024];
  __shared__ int soff[NE];
  int tid = threadIdx.x;

  if (blockIdx.x < 4096) {
    // ---- W1 transpose+convert: one 64x64 tile ----
    int wid = blockIdx.x;
    int e = wid >> 9;
    int rem = wid & 511;
    int kb = rem >> 5;
    int hb = rem & 31;
    const float* src = W1 + ((size_t)e * ND + kb * 64) * NH + hb * 64;
    int kl = tid >> 4;
    int h0 = (tid & 15) * 4;
    f32x4 v = *(const f32x4*)(src + (size_t)kl * NH + h0);
    tile[kl][h0 + 0] = v[0];
    tile[kl][h0 + 1] = v[1];
    tile[kl][h0 + 2] = v[2];
    tile[kl][h0 + 3] = v[3];
    __syncthreads();
    unsigned short* dst = w1t + ((size_t)e * NH + hb * 64) * ND + kb * 64;
    int hl = tid >> 4;
    int kq = (tid & 15) * 4;
    short4v s;
#pragma unroll
    for (int j = 0; j < 4; ++j) s[j] = (short)f2bf(tile[kq + j][hl]);
    *(short4v*)(dst + (size_t)hl * ND + kq) = s;  // 8B/lane coalesced
    return;
  }

  // ---- ranker ----
  int t[16];
  const int4* tp = (const int4*)(topics + tid * 16);
#pragma unroll
  for (int i = 0; i < 4; ++i) {
    int4 v = tp[i];
    t[i * 4 + 0] = v.x; t[i * 4 + 1] = v.y;
    t[i * 4 + 2] = v.z; t[i * 4 + 3] = v.w;
  }
  int h[NE] = {0, 0, 0, 0, 0, 0, 0, 0};
#pragma unroll
  for (int i = 0; i < 16; ++i) {
#pragma unroll
    for (int q = 0; q < NE; ++q) h[q] += (t[i] == q);
  }
  uint4 pk;
  pk.x = (unsigned)h[0] | ((unsigned)h[1] << 16);
  pk.y = (unsigned)h[2] | ((unsigned)h[3] << 16);
  pk.z = (unsigned)h[4] | ((unsigned)h[5] << 16);
  pk.w = (unsigned)h[6] | ((unsigned)h[7] << 16);
  uint4 own = pk;
  sbuf[tid] = pk;
  __syncthreads();
  for (int d = 1; d < 1024; d <<= 1) {
    uint4 v = {0u, 0u, 0u, 0u};
    if (tid >= d) v = sbuf[tid - d];
    __syncthreads();
    pk.x += v.x; pk.y += v.y; pk.z += v.z; pk.w += v.w;
    sbuf[tid] = pk;
    __syncthreads();
  }
  if (tid == 0) {
    uint4 tot = sbuf[1023];
    int c[NE] = {(int)(tot.x & 0xffff), (int)(tot.x >> 16),
                 (int)(tot.y & 0xffff), (int)(tot.y >> 16),
                 (int)(tot.z & 0xffff), (int)(tot.z >> 16),
                 (int)(tot.w & 0xffff), (int)(tot.w >> 16)};
    int s = 0, nw = 0;
    for (int e = 0; e < NE; ++e) {
      counts[e] = c[e];
      offsets[e] = s;
      soff[e] = s;
      s += c[e];
      for (int mt = 0; mt * 128 < c[e]; ++mt) worklist[nw++] = (e << 16) | mt;
    }
    *n_wl = nw;
  }
  __syncthreads();
  uint4 ex;
  ex.x = pk.x - own.x; ex.y = pk.y - own.y;
  ex.z = pk.z - own.z; ex.w = pk.w - own.w;
  int r[NE] = {soff[0] + (int)(ex.x & 0xffff), soff[1] + (int)(ex.x >> 16),
               soff[2] + (int)(ex.y & 0xffff), soff[3] + (int)(ex.y >> 16),
               soff[4] + (int)(ex.z & 0xffff), soff[5] + (int)(ex.z >> 16),
               soff[6] + (int)(ex.w & 0xffff), soff[7] + (int)(ex.w >> 16)};
#pragma unroll
  for (int i = 0; i < 16; ++i) {
    int e = t[i];
    int pos = 0;
#pragma unroll
    for (int q = 0; q < NE; ++q) pos = (e == q) ? r[q] : pos;
    perm[pos] = tid * 16 + i;
#pragma unroll
    for (int q = 0; q < NE; ++q) r[q] += (e == q);
  }
}

// ---------------------------------------------------------------------------
// Kernel 3: fused gathered GEMM + bias/relu + W2 reduce -> PARTIALS.
// 128x128 tile, BK=32, 32 K-tiles, 4 waves x (4x4) 16x16x32 bf16 frags.
// Round-8 fixes vs round 7 (counter-driven):
//  - SWIZZLE BUG FIX: round-7's chunk XOR ^(r&3) gave 4-way bank conflicts
//    (8.65M): within a 16-lane group the bank base cg*16 mod 32 depends only
//    on cg&1, so lanes sharing cg&3 collided. New swizzle XORs (row>>1)&3:
//    stage source cs0 = (t&3)^((t>>3)&3); read chunk = g^((cg>>1)&3).
//    -> 2 lanes/bank within each group (free, m136).
//  - SPILL FIX: __launch_bounds__(256,3) (not 4): 170-reg budget leaves
//    ~106 VGPR + 64 AGPR with NO scratch spill (round 7's (256,4) forced
//    VGPR=64 and ~30MB of scratch HBM writes). LDS 33KB x 3 = 99KB/CU.
// ---------------------------------------------------------------------------
#define MF(a, b, c) __builtin_amdgcn_mfma_f32_16x16x32_bf16((a), (b), (c), 0, 0, 0)

#define STAGE(AS, BS, kt)                                       \
  do {                                                          \
    glds16(aptr0 + (kt), (char*)(AS) + (size_t)t * 16);         \
    glds16(aptr1 + (kt), (char*)(AS) + (size_t)(256 + t) * 16); \
    glds16(bptr0 + (kt), (char*)(BS) + (size_t)t * 16);         \
    glds16(bptr1 + (kt), (char*)(BS) + (size_t)(256 + t) * 16); \
  } while (0)

#define COMPUTE(AS, BS)                                               \
  do {                                                                \
    short8 af_[4], bf_[4];                                            \
    _Pragma("unroll") for (int m_ = 0; m_ < 4; ++m_)                  \
        af_[m_] = *(const short8*)&(AS)[arow_e + m_ * 512 + ch8];     \
    _Pragma("unroll") for (int n_ = 0; n_ < 4; ++n_)                  \
        bf_[n_] = *(const short8*)&(BS)[brow_e + n_ * 512 + ch8];     \
    _Pragma("unroll") for (int m_ = 0; m_ < 4; ++m_)                  \
        _Pragma("unroll") for (int n_ = 0; n_ < 4; ++n_)              \
            acc[m_][n_] = MF(af_[m_], bf_[n_], acc[m_][n_]);          \
  } while (0)

__global__ __launch_bounds__(256, 3) void moe_gemm_kernel(
    const unsigned short* __restrict__ xb, const unsigned short* __restrict__ w1t,
    const float* __restrict__ b1, const float* __restrict__ W2,
    const int* __restrict__ perm, const int* __restrict__ counts,
    const int* __restrict__ offsets, const int* __restrict__ worklist,
    const int* __restrict__ n_wl, float* __restrict__ partial) {
  int nt = blockIdx.x & 15;  // B panel; XCD = bid%8 -> B L2-local
  int wi = blockIdx.x >> 4;
  if (wi >= *n_wl) return;
  int item = worklist[wi];
  int e = item >> 16;
  int mt = item & 0xffff;
  int cnt = counts[e];
  int off = offsets[e];
  int t = threadIdx.x;
  int lane = t & 63;
  int w = t >> 6, wr = w >> 1, wc = w & 1;

  __shared__ int ridx[128];
  __shared__ unsigned short As0[128 * 32];  // slot(r,c): global chunk c^((r>>1)&3)
  __shared__ unsigned short Bs0[128 * 32];
  __shared__ unsigned short As1[128 * 32];
  __shared__ unsigned short Bs1[128 * 32];

  if (t < 128) {
    int m = mt * 128 + t;
    ridx[t] = perm[off + (m < cnt ? m : cnt - 1)];
  }
  __syncthreads();

  // staging: thread t covers 16B chunks idx=t and idx=256+t of each tile.
  // idx -> row r=idx>>2, chunk c=idx&3; source chunk cs = c ^ ((r>>1)&3).
  // (r for idx=256+t is 64+r0: ((64+r0)>>1)&3 == (r0>>1)&3, so cs shared.)
  int r0 = t >> 2;
  int cs0 = (t & 3) ^ ((t >> 3) & 3);
  const unsigned short* aptr0 = xb + (size_t)ridx[r0] * ND + cs0 * 8;
  const unsigned short* aptr1 = xb + (size_t)ridx[64 + r0] * ND + cs0 * 8;
  const unsigned short* bptr0 =
      w1t + ((size_t)(e * NH + nt * 128 + r0)) * ND + cs0 * 8;
  const unsigned short* bptr1 =
      w1t + ((size_t)(e * NH + nt * 128 + 64 + r0)) * ND + cs0 * 8;

  // hoist epilogue weights above K-loop
  int cg = lane & 15;
  int g = lane >> 4;
  float b1v[4];
  float w2v[4][3];
#pragma unroll
  for (int n = 0; n < 4; ++n) {
    int col = nt * 128 + wc * 64 + n * 16 + cg;
    b1v[n] = b1[e * NH + col];
    const float* w2p = W2 + ((size_t)e * NH + col) * NC;
    w2v[n][0] = w2p[0];
    w2v[n][1] = w2p[1];
    w2v[n][2] = w2p[2];
  }

  f32x4 acc[4][4];
#pragma unroll
  for (int m = 0; m < 4; ++m)
#pragma unroll
    for (int n = 0; n < 4; ++n) acc[m][n] = (f32x4){0.f, 0.f, 0.f, 0.f};

  int arow_e = (wr * 64 + cg) * 32;
  int brow_e = (wc * 64 + cg) * 32;
  int ch8 = (g ^ ((cg >> 1) & 3)) * 8;  // swizzled chunk for this lane

  // double-buffered K-loop: 32 tiles of BK=32
  STAGE(As0, Bs0, 0);
  __syncthreads();
#pragma unroll 1
  for (int it = 0; it < 15; ++it) {
    int kb = it * 64;
    STAGE(As1, Bs1, kb + 32);
    COMPUTE(As0, Bs0);
    __syncthreads();
    STAGE(As0, Bs0, kb + 64);
    COMPUTE(As1, Bs1);
    __syncthreads();
  }
  STAGE(As1, Bs1, 992);
  COMPUTE(As0, Bs0);  // tile kt=960
  __syncthreads();
  COMPUTE(As1, Bs1);  // tile kt=992

  // Epilogue: h = relu(acc + b1); partial[wi][nt][wc][row][c] = this wave's
  // 64-h-col contribution.  C/D frag: col=lane&15, row=(lane>>4)*4+i [m89].
  float* pbase = partial + (((size_t)(wi * 16 + nt)) * 2 + wc) * 128 * NC;
#pragma unroll
  for (int m = 0; m < 4; ++m) {
#pragma unroll
    for (int i = 0; i < 4; ++i) {
      float s0 = 0.f, s1 = 0.f, s2 = 0.f;
#pragma unroll
      for (int n = 0; n < 4; ++n) {
        float h = acc[m][n][i] + b1v[n];
        h = h > 0.f ? h : 0.f;
        s0 = fmaf(h, w2v[n][0], s0);
        s1 = fmaf(h, w2v[n][1], s1);
        s2 = fmaf(h, w2v[n][2], s2);
      }
#pragma unroll
      for (int d = 1; d < 16; d <<= 1) {
        s0 += __shfl_xor(s0, d);
        s1 += __shfl_xor(s1, d);
        s2 += __shfl_xor(s2, d);
      }
      if (cg == 0) {
        int rloc = wr * 64 + m * 16 + g * 4 + i;
        float* pp = pbase + rloc * NC;
        pp[0] = s0;
        pp[1] = s1;
        pp[2] = s2;
      }
    }
  }
}

// ---------------------------------------------------------------------------
// Kernel 4: reduce partials over (nt, wc) and write out = b2[e] + sum.
// One block per worklist tile; 384 threads = (row,c) pairs; sum 32 slots.
// ---------------------------------------------------------------------------
__global__ __launch_bounds__(384) void reduce_kernel(
    const float* __restrict__ partial, const float* __restrict__ b2,
    const int* __restrict__ perm, const int* __restrict__ counts,
    const int* __restrict__ offsets, const int* __restrict__ worklist,
    const int* __restrict__ n_wl, float* __restrict__ out) {
  int wi = blockIdx.x;
  if (wi >= *n_wl) return;
  int item = worklist[wi];
  int e = item >> 16;
  int mt = item & 0xffff;
  int cnt = counts[e];
  int off = offsets[e];
  int j = threadIdx.x;  // row*3 + c
  int r = j / 3, c = j - r * 3;
  int m = mt * 128 + r;
  if (m >= cnt) return;
  const float* p = partial + (size_t)wi * 32 * 384 + j;
  float s = 0.f;
#pragma unroll
  for (int q = 0; q < 32; ++q) s += p[q * 384];
  int tok = perm[off + m];
  out[tok * NC + c] = b2[e * NC + c] + s;
}

// ---------------------------------------------------------------------------
// Workspace layout (~74 MB):
//   [0,   32MiB)       xb  bf16 [16384][1024]
//   [32,  64MiB)       W1T bf16 [8][2048][1024]
//   [64MiB, +132KB)    topics[16384], perm[16384], counts[8], offsets[8],
//                      worklist[256], n_wl
//   [64MiB+132KB, ...) partial f32 [136*16][2][128][3]  (6.68 MB)
// (gemm A-tail duplicate rows produce partials for rloc>=cnt; reduce guards.)
// ---------------------------------------------------------------------------
extern "C" void kernel_launch(void* const* d_in, const int* in_sizes, int n_in,
                              void* d_out, int out_size, void* d_ws,
                              size_t ws_size, hipStream_t stream) {
  const float* x = (const float*)d_in[0];
  const float* Wr = (const float*)d_in[1];
  const float* br = (const float*)d_in[2];
  const float* W1 = (const float*)d_in[3];
  const float* b1 = (const float*)d_in[4];
  const float* W2 = (const float*)d_in[5];
  const float* b2 = (const float*)d_in[6];
  float* out = (float*)d_out;

  char* ws = (char*)d_ws;
  unsigned short* xb = (unsigned short*)ws;
  unsigned short* w1t = (unsigned short*)(ws + (size_t)33554432);
  int* topics = (int*)(ws + (size_t)67108864);
  int* perm = topics + NB;
  int* counts = perm + NB;
  int* offsets = counts + NE;
  int* worklist = offsets + NE;
  int* n_wl = worklist + 256;
  float* partial = (float*)(ws + (size_t)67108864 + 135168);

  router_kernel<<<NB / 4, 256, 0, stream>>>(x, Wr, br, xb, topics);
  ranker_w1t_kernel<<<4097, 1024, 0, stream>>>(topics, W1, w1t, perm, counts,
                                               offsets, worklist, n_wl);
  moe_gemm_kernel<<<MAXWL * 16, 256, 0, stream>>>(xb, w1t, b1, W2, perm,
                                                  counts, offsets, worklist,
                                                  n_wl, partial);
  reduce_kernel<<<MAXWL, 384, 0, stream>>>(partial, b2, perm, counts, offsets,
                                           worklist, n_wl, out);
}